// Round 1
// baseline (398.416 us; speedup 1.0000x reference)
//
#include <hip/hip_runtime.h>
#include <hip/hip_bf16.h>
#include <cstdint>

#define Bb 2
#define Nc 6
#define Qn 900
#define Cc 256
#define Hc 116
#define Wc 200
#define EPSf 1e-5f

struct Proj { int x0, y0; float wx, wy; };  // 16 B, x0==INT32_MIN => invalid

// ---------------- Kernel A: project reference points through lidar2img ----------------
__global__ void proj_kernel(const float* __restrict__ ref_pts,   // (B, Q, 3)
                            const float* __restrict__ l2i,       // (B, N, 4, 4)
                            Proj* __restrict__ proj) {           // (B*N, Q)
    int t = blockIdx.x * blockDim.x + threadIdx.x;
    if (t >= Bb * Nc * Qn) return;
    int q  = t % Qn;
    int bn = t / Qn;            // b*Nc + n
    int b  = bn / Nc;

    const float* p = ref_pts + ((size_t)b * Qn + q) * 3;
    float px = p[0], py = p[1], pz = p[2];
    const float* M = l2i + (size_t)bn * 16;
    float h0 = M[0]*px + M[1]*py + M[2]*pz  + M[3];
    float h1 = M[4]*px + M[5]*py + M[6]*pz  + M[7];
    float h2 = M[8]*px + M[9]*py + M[10]*pz + M[11];

    float denom = fabsf(h2) + EPSf;
    float x2d = h0 / denom;
    float y2d = h1 / denom;
    // match reference op order: pts / (W-1) * 2 - 1
    float gx = x2d / (float)(Wc - 1) * 2.0f - 1.0f;
    float gy = y2d / (float)(Hc - 1) * 2.0f - 1.0f;
    bool front = h2 > EPSf;
    bool in_img = fmaxf(fabsf(gx), fabsf(gy)) <= 1.0f;

    Proj o;
    if (front && in_img) {
        // align_corners=False mapping
        float x = ((gx + 1.0f) * (float)Wc - 1.0f) * 0.5f;
        float y = ((gy + 1.0f) * (float)Hc - 1.0f) * 0.5f;
        float x0f = floorf(x), y0f = floorf(y);
        o.x0 = (int)x0f;
        o.y0 = (int)y0f;
        o.wx = x - x0f;
        o.wy = y - y0f;
    } else {
        o.x0 = INT32_MIN; o.y0 = 0; o.wx = 0.0f; o.wy = 0.0f;
    }
    proj[t] = o;
}

// ---------------- Kernel B: bilinear gather + masked mean over cameras ----------------
// block = one (b,q), thread = channel c. Wave-uniform skip of invalid cameras.
__global__ void sample_kernel(const float* __restrict__ feats,   // (B*N, C, H, W)
                              const Proj* __restrict__ proj,     // (B*N, Q)
                              float* __restrict__ agg) {         // (B*Q, C), mean already applied
    int bq = blockIdx.x;            // 0 .. B*Qn-1
    int b  = bq / Qn;
    int q  = bq % Qn;
    int c  = threadIdx.x;           // 0..255

    float acc = 0.0f;
    #pragma unroll
    for (int n = 0; n < Nc; ++n) {
        int bn = b * Nc + n;
        Proj pr = proj[(size_t)bn * Qn + q];       // uniform across block -> scalar load
        if (pr.x0 == INT32_MIN) continue;          // uniform branch

        const float* img = feats + ((size_t)bn * Cc + c) * (size_t)(Hc * Wc);
        int x0 = pr.x0, y0 = pr.y0, x1 = x0 + 1, y1 = y0 + 1;
        float wx = pr.wx, wy = pr.wy;

        bool vx0 = (x0 >= 0) & (x0 < Wc);
        bool vx1 = (x1 >= 0) & (x1 < Wc);
        bool vy0 = (y0 >= 0) & (y0 < Hc);
        bool vy1 = (y1 >= 0) & (y1 < Hc);
        int cx0 = min(max(x0, 0), Wc - 1);
        int cx1 = min(max(x1, 0), Wc - 1);
        int cy0 = min(max(y0, 0), Hc - 1);
        int cy1 = min(max(y1, 0), Hc - 1);

        float v00 = img[cy0 * Wc + cx0] * ((vx0 & vy0) ? 1.0f : 0.0f);
        float v01 = img[cy0 * Wc + cx1] * ((vx1 & vy0) ? 1.0f : 0.0f);
        float v10 = img[cy1 * Wc + cx0] * ((vx0 & vy1) ? 1.0f : 0.0f);
        float v11 = img[cy1 * Wc + cx1] * ((vx1 & vy1) ? 1.0f : 0.0f);

        acc += (v00 * (1.0f - wx) + v01 * wx) * (1.0f - wy)
             + (v10 * (1.0f - wx) + v11 * wx) * wy;
    }
    agg[(size_t)bq * Cc + c] = acc * (1.0f / 6.0f);
}

// ---------------- Kernel C: out = agg @ W_out^T + b_out ----------------
// block covers QT query rows; thread = output channel. W_out row read as float4,
// agg tile staged in LDS (broadcast reads, conflict-free).
#define QT 8
__global__ void out_gemm(const float* __restrict__ agg,    // (B*Q, C)
                         const float* __restrict__ Wm,     // (C, C) row-major: Wm[co*C + c]
                         const float* __restrict__ bias,   // (C,)
                         float* __restrict__ out) {        // (B*Q, C)
    __shared__ float sA[QT][Cc];
    int base_q = blockIdx.x * QT;
    int tid = threadIdx.x;          // 0..255 = co

    for (int i = tid; i < QT * Cc; i += 256)
        sA[i / Cc][i % Cc] = agg[(size_t)base_q * Cc + i];
    __syncthreads();

    float acc[QT];
    #pragma unroll
    for (int j = 0; j < QT; ++j) acc[j] = 0.0f;

    const float4* wrow = (const float4*)(Wm + (size_t)tid * Cc);
    #pragma unroll 4
    for (int c4 = 0; c4 < Cc / 4; ++c4) {
        float4 w = wrow[c4];
        #pragma unroll
        for (int j = 0; j < QT; ++j) {
            acc[j] += w.x * sA[j][4*c4 + 0] + w.y * sA[j][4*c4 + 1]
                    + w.z * sA[j][4*c4 + 2] + w.w * sA[j][4*c4 + 3];
        }
    }
    float bb = bias[tid];
    #pragma unroll
    for (int j = 0; j < QT; ++j)
        out[(size_t)(base_q + j) * Cc + tid] = acc[j] + bb;
}

extern "C" void kernel_launch(void* const* d_in, const int* in_sizes, int n_in,
                              void* d_out, int out_size, void* d_ws, size_t ws_size,
                              hipStream_t stream) {
    // inputs: 0=query (unused), 1=reference_points, 2=image_features, 3=lidar2img, 4=W_out, 5=b_out
    const float* ref_pts = (const float*)d_in[1];
    const float* feats   = (const float*)d_in[2];
    const float* l2i     = (const float*)d_in[3];
    const float* Wm      = (const float*)d_in[4];
    const float* bias    = (const float*)d_in[5];
    float* out = (float*)d_out;

    size_t proj_bytes = (size_t)Bb * Nc * Qn * sizeof(Proj);
    proj_bytes = (proj_bytes + 255) & ~(size_t)255;
    Proj*  proj = (Proj*)d_ws;
    float* agg  = (float*)((char*)d_ws + proj_bytes);

    int npts = Bb * Nc * Qn;
    proj_kernel<<<(npts + 255) / 256, 256, 0, stream>>>(ref_pts, l2i, proj);
    sample_kernel<<<Bb * Qn, 256, 0, stream>>>(feats, proj, agg);
    out_gemm<<<(Bb * Qn) / QT, 256, 0, stream>>>(agg, Wm, bias, out);
}